// Round 1
// baseline (26991.220 us; speedup 1.0000x reference)
//
#include <hip/hip_runtime.h>

#define T_STEPS 128
#define BATCH   64
#define INDIM   512
#define HDIM    1024
#define NLAYER  3
#define NE      819            /* int(1024*0.8) */
#define OUT0_SZ (T_STEPS*BATCH*HDIM)
#define BH      (BATCH*HDIM)
#define ALLH_L  (129*BH)       /* per-layer stride in all_hiddens */

// Init: all_hiddens[l][0] = hidden_init; v_state = 0
__global__ __launch_bounds__(256) void ei_init(const float* __restrict__ h0,
                                               float* __restrict__ out,
                                               float* __restrict__ v_ws) {
    int idx = blockIdx.x * 256 + threadIdx.x;       // 0 .. 3*BH-1
    int l = idx >> 16;                              // BH == 65536
    int r = idx & 0xFFFF;
    float* all_h = out + OUT0_SZ;
    all_h[l * ALLH_L + r] = h0[r];
    v_ws[idx] = 0.0f;
}

// One skewed pipeline step: layer j processes timestep t = s - j.
// Block tile: [64 batch x 16 cols]. 64 blocks per layer, 3 layers -> grid 192.
__global__ __launch_bounds__(256) void ei_stage(
    const float* __restrict__ xin,
    const float* __restrict__ Win0,
    const float* __restrict__ Win1,
    const float* __restrict__ Win2,
    const float* __restrict__ Wrec,
    const float* __restrict__ bias,
    float* __restrict__ out,
    float* __restrict__ v_ws,
    int s)
{
    const int j  = blockIdx.x >> 6;
    const int cb = blockIdx.x & 63;
    const int t  = s - j;
    if (t < 0 || t >= T_STEPS) return;

    float* all_h = out + OUT0_SZ;
    const float* Win = (j == 0) ? Win0 : (j == 1 ? Win1 : Win2);
    const int K1 = (j == 0) ? INDIM : HDIM;
    const float* Wr = Wrec + j * HDIM * HDIM;
    const float* ffp; int ffld;
    if (j == 0) { ffp = xin + t * BATCH * INDIM; ffld = INDIM; }
    else        { ffp = all_h + ((j - 1) * 129 + (t + 1)) * BH; ffld = HDIM; }
    const float* hj = all_h + (j * 129 + t) * BH;   // h_j(t-1) ... stored at index t

    __shared__ float Xs[64][68];   // transposed input chunk: Xs[k][b], padded
    __shared__ float Ws[16][65];   // |W| rows for this block's 16 cols

    const int tx = threadIdx.x;
    const int i_loc = tx & 15;
    const int b0 = (tx >> 4) * 4;
    const int i0 = cb * 16;

    float acc0 = 0.f, acc1 = 0.f, acc2 = 0.f, acc3 = 0.f;

    const int nch_ff = K1 >> 6;             // 8 (layer 0) or 16
    const int nch = nch_ff + (HDIM >> 6);   // + 16 recurrent chunks

    for (int ch = 0; ch < nch; ++ch) {
        const bool ff = ch < nch_ff;
        const int kb = ff ? (ch << 6) : ((ch - nch_ff) << 6);
        __syncthreads();
        // Stage X chunk (64 k x 64 b), transform applied at load:
        //   ff (j>0): h_{j-1}(t) * e_mask ; ff (j==0): x_t ; rec: h_j(t-1) * sign_k
        #pragma unroll
        for (int it = 0; it < 16; ++it) {
            int idx = it * 256 + tx;
            int bl = idx >> 6;
            int kl = idx & 63;
            int k = kb + kl;
            float v;
            if (ff) {
                v = ffp[bl * ffld + k];
                if (j != 0 && k >= NE) v = 0.0f;
            } else {
                v = hj[bl * HDIM + k];
                if (k >= NE) v = -v;
            }
            Xs[kl][bl] = v;
        }
        // Stage |W| chunk (16 cols x 64 k)
        const float* W = ff ? Win : Wr;
        const int ldw = ff ? K1 : HDIM;
        #pragma unroll
        for (int it = 0; it < 4; ++it) {
            int idx = it * 256 + tx;
            int il = idx >> 6;
            int kl = idx & 63;
            Ws[il][kl] = fabsf(W[(i0 + il) * ldw + kb + kl]);
        }
        __syncthreads();
        // Inner product: thread owns cols i0+i_loc, batch rows b0..b0+3
        #pragma unroll
        for (int kk = 0; kk < 64; ++kk) {
            const float w = Ws[i_loc][kk];
            const float4 x4 = *reinterpret_cast<const float4*>(&Xs[kk][b0]);
            acc0 = fmaf(x4.x, w, acc0);
            acc1 = fmaf(x4.y, w, acc1);
            acc2 = fmaf(x4.z, w, acc2);
            acc3 = fmaf(x4.w, w, acc3);
        }
    }

    // Epilogue: leaky integration, ReLU, state + output writes
    const int i = i0 + i_loc;
    const float bj = bias[j * HDIM + i];
    float accs[4] = {acc0, acc1, acc2, acc3};
    #pragma unroll
    for (int r = 0; r < 4; ++r) {
        const int b = b0 + r;
        const float pre = accs[r] + bj;
        float* vp = v_ws + (j * BATCH + b) * HDIM + i;
        const float vn = 0.8f * (*vp) + 0.2f * pre;
        *vp = vn;
        const float h = vn > 0.f ? vn : 0.f;
        all_h[(j * 129 + (t + 1)) * BH + b * HDIM + i] = h;
        if (j == 2) out[(t * BATCH + b) * HDIM + i] = (i < NE) ? h : 0.f;
    }
}

extern "C" void kernel_launch(void* const* d_in, const int* in_sizes, int n_in,
                              void* d_out, int out_size, void* d_ws, size_t ws_size,
                              hipStream_t stream) {
    const float* xin  = (const float*)d_in[0];
    const float* h0   = (const float*)d_in[1];
    const float* Win0 = (const float*)d_in[2];
    const float* Win1 = (const float*)d_in[3];
    const float* Win2 = (const float*)d_in[4];
    const float* Wrec = (const float*)d_in[5];
    const float* bias = (const float*)d_in[6];
    float* out  = (float*)d_out;
    float* v_ws = (float*)d_ws;

    hipLaunchKernelGGL(ei_init, dim3((NLAYER * BH) / 256), dim3(256), 0, stream,
                       h0, out, v_ws);
    for (int s = 0; s < T_STEPS + NLAYER - 1; ++s) {
        hipLaunchKernelGGL(ei_stage, dim3(64 * NLAYER), dim3(256), 0, stream,
                           xin, Win0, Win1, Win2, Wrec, bias, out, v_ws, s);
    }
}

// Round 2
// 3952.080 us; speedup vs baseline: 6.8296x; 6.8296x over previous
//
#include <hip/hip_runtime.h>

#define T_STEPS 128
#define BATCH   64
#define INDIM   512
#define HDIM    1024
#define NE      819
#define OUT0_SZ (T_STEPS*BATCH*HDIM)
#define BH      (BATCH*HDIM)          /* 65536 */
#define ALLH_L  (129*BH)

/* ---- workspace layout (bytes) ---- */
#define WS_V    0                     /* fp32 v-state: 3*64*1024*4 = 786432 */
#define WS_HS   786432                /* bf16 h split, 2 parities: 2*3*2*65536*2 = 1572864 */
#define WS_XHI  2359296               /* bf16 x hi: 4194304*2 */
#define WS_XLO  10747904              /* bf16 x lo */
#define WS_WF   19136512              /* bf16 weight fragments: 11534336*2 */
#define WS_NEED 42205184
#define HS_PAR  393216                /* elements per parity */
#define HS_LAY  131072

typedef short bf16x8 __attribute__((ext_vector_type(8)));
typedef short s16x4  __attribute__((ext_vector_type(4)));
typedef float f32x4  __attribute__((ext_vector_type(4)));

__device__ __forceinline__ short f2bf(float f){
    unsigned u = __float_as_uint(f);
    u += 0x7FFF + ((u >> 16) & 1);           /* RNE */
    return (short)(u >> 16);
}
__device__ __forceinline__ float bf2f(short s){
    return __uint_as_float(((unsigned)(unsigned short)s) << 16);
}

/* ============ one-time prep: weights -> |.|*sign*emask, split hi/lo, frag-swizzled ============ */
/* layout per layer: [it(64)][kb(nkb)][hi/lo][lane(64)][8] bf16; L0 nkb=48, L1/2 nkb=64 */
__global__ __launch_bounds__(256) void ei_prep_w(const float* __restrict__ Win0,
        const float* __restrict__ Win1, const float* __restrict__ Win2,
        const float* __restrict__ Wrec, short* __restrict__ wf){
    int gid = blockIdx.x * 256 + threadIdx.x;      /* 0 .. 720895 */
    int j, local, nkb, kff; const float* Win; short* base;
    if (gid < 196608)      { j=0; local=gid;        nkb=48; kff=512;  Win=Win0; base=wf; }
    else if (gid < 458752) { j=1; local=gid-196608; nkb=64; kff=1024; Win=Win1; base=wf+3145728; }
    else                   { j=2; local=gid-458752; nkb=64; kff=1024; Win=Win2; base=wf+7340032; }
    int lane = local & 63;
    int fi   = local >> 6;                         /* it*nkb + kb */
    int kb   = fi % nkb;
    int it   = fi / nkb;
    int i    = it*16 + (lane & 15);
    int k0   = kb*32 + ((lane >> 4) << 3);
    const float* wrec_row = Wrec + ((size_t)j*HDIM + i)*HDIM;
    bf16x8 hv, lv;
    #pragma unroll
    for (int e = 0; e < 8; ++e){
        int k = k0 + e;
        float w;
        if (k < kff){
            w = fabsf(Win[(size_t)i*kff + k]);
            if (j != 0 && k >= NE) w = 0.f;        /* e_mask folded into ff weights */
        } else {
            int kr = k - kff;
            w = fabsf(wrec_row[kr]);
            if (kr >= NE) w = -w;                  /* Dale sign folded */
        }
        short h = f2bf(w);
        hv[e] = h;
        lv[e] = f2bf(w - bf2f(h));
    }
    short* dst = base + (size_t)fi*1024 + lane*8;
    *(bf16x8*)dst         = hv;
    *(bf16x8*)(dst + 512) = lv;
}

/* ============ one-time prep: split all inputs x into bf16 hi/lo planes ============ */
__global__ __launch_bounds__(256) void ei_prep_x(const float* __restrict__ x,
        short* __restrict__ xhi, short* __restrict__ xlo){
    int gid = blockIdx.x * 256 + threadIdx.x;      /* 0 .. 1048575, 4 elems each */
    float4 v = ((const float4*)x)[gid];
    s16x4 hv, lv;
    float f[4] = {v.x, v.y, v.z, v.w};
    #pragma unroll
    for (int e = 0; e < 4; ++e){
        short h = f2bf(f[e]);
        hv[e] = h; lv[e] = f2bf(f[e] - bf2f(h));
    }
    ((s16x4*)xhi)[gid] = hv;
    ((s16x4*)xlo)[gid] = lv;
}

/* ============ init: all_h[l][0]=h0, v=0, h-split both parities ============ */
__global__ __launch_bounds__(256) void ei_init2(const float* __restrict__ h0,
        float* __restrict__ out, float* __restrict__ v_ws, short* __restrict__ hs){
    int idx = blockIdx.x * 256 + threadIdx.x;      /* 0 .. 196607 */
    int l = idx >> 16, r = idx & 0xFFFF;
    float h = h0[r];
    out[OUT0_SZ + (size_t)l*ALLH_L + r] = h;
    v_ws[idx] = 0.f;
    short hh = f2bf(h), hl = f2bf(h - bf2f(hh));
    hs[          l*HS_LAY + r]         = hh;
    hs[          l*HS_LAY + 65536 + r] = hl;
    hs[HS_PAR +  l*HS_LAY + r]         = hh;
    hs[HS_PAR +  l*HS_LAY + 65536 + r] = hl;
}

/* ============ skewed step, MFMA split-bf16. grid = 96 blocks (3 layers x 4 bt x 8 ib) ============ */
__global__ __launch_bounds__(256) void ei_stage2(
        const short* __restrict__ xhi, const short* __restrict__ xlo,
        const short* __restrict__ wf,  const float* __restrict__ bias,
        float* __restrict__ out, float* __restrict__ v_ws,
        short* __restrict__ hs, int s)
{
    int j = blockIdx.x >> 5;
    int t = s - j;
    if (t < 0 || t >= T_STEPS) return;
    int rem = blockIdx.x & 31;
    int bt = rem >> 3, ib = rem & 7;
    int wv = threadIdx.x >> 6, lane = threadIdx.x & 63;
    int it0 = ib*8 + wv*2;                          /* this wave: i-tiles it0, it0+1 */
    int par_r = (s - 1) & 1, par_w = s & 1;

    int nkb, nkff, ldff;
    const short *ffh, *ffl;
    if (j == 0){
        nkb = 48; nkff = 16; ldff = INDIM;
        ffh = xhi + (size_t)t*BATCH*INDIM;
        ffl = xlo + (size_t)t*BATCH*INDIM;
    } else {
        nkb = 64; nkff = 32; ldff = HDIM;
        const short* b0 = hs + par_r*HS_PAR + (j-1)*HS_LAY;
        ffh = b0; ffl = b0 + 65536;
    }
    const short* rbase = hs + par_r*HS_PAR + j*HS_LAY;

    int br   = bt*16 + (lane & 15);                 /* batch row this lane feeds A with */
    int kloc = (lane >> 4) << 3;
    const short* affh = ffh + (size_t)br*ldff + kloc;
    const short* affl = ffl + (size_t)br*ldff + kloc;
    const short* arh  = rbase +          (size_t)br*HDIM + kloc;
    const short* arl  = rbase + 65536 +  (size_t)br*HDIM + kloc;
    const short* wfj  = wf + (j==0 ? 0 : (j==1 ? 3145728 : 7340032));
    const short* wp0  = wfj + (size_t)it0*nkb*1024 + lane*8;

    f32x4 acc0 = {0.f,0.f,0.f,0.f}, acc1 = {0.f,0.f,0.f,0.f};

    #pragma unroll 2
    for (int kb = 0; kb < nkb; ++kb){
        bf16x8 ah, al;
        if (kb < nkff){ ah = *(const bf16x8*)(affh + kb*32); al = *(const bf16x8*)(affl + kb*32); }
        else { int kr = (kb - nkff)*32; ah = *(const bf16x8*)(arh + kr); al = *(const bf16x8*)(arl + kr); }
        const short* w0 = wp0 + kb*1024;
        bf16x8 bh0 = *(const bf16x8*)w0;
        bf16x8 bl0 = *(const bf16x8*)(w0 + 512);
        const short* w1 = w0 + nkb*1024;
        bf16x8 bh1 = *(const bf16x8*)w1;
        bf16x8 bl1 = *(const bf16x8*)(w1 + 512);
        acc0 = __builtin_amdgcn_mfma_f32_16x16x32_bf16(ah, bh0, acc0, 0,0,0);
        acc1 = __builtin_amdgcn_mfma_f32_16x16x32_bf16(ah, bh1, acc1, 0,0,0);
        acc0 = __builtin_amdgcn_mfma_f32_16x16x32_bf16(al, bh0, acc0, 0,0,0);
        acc1 = __builtin_amdgcn_mfma_f32_16x16x32_bf16(al, bh1, acc1, 0,0,0);
        acc0 = __builtin_amdgcn_mfma_f32_16x16x32_bf16(ah, bl0, acc0, 0,0,0);
        acc1 = __builtin_amdgcn_mfma_f32_16x16x32_bf16(ah, bl1, acc1, 0,0,0);
    }

    /* epilogue: C/D layout col=lane&15, row=(lane>>4)*4+r  [m89-verified] */
    float* allh = out + OUT0_SZ + ((size_t)(j*129 + t + 1))*BH;
    float* outp = out + (size_t)t*BH;
    short* hwh  = hs + par_w*HS_PAR + j*HS_LAY;
    short* hwl  = hwh + 65536;
    int b0 = bt*16 + ((lane >> 4) << 2);
    f32x4 accs[2] = {acc0, acc1};
    #pragma unroll
    for (int c = 0; c < 2; ++c){
        int i = (it0 + c)*16 + (lane & 15);
        float bb = bias[j*HDIM + i];
        #pragma unroll
        for (int r = 0; r < 4; ++r){
            int b = b0 + r;
            size_t vo = ((size_t)j*BATCH + b)*HDIM + i;
            float pre = accs[c][r] + bb;
            float vn  = 0.8f * v_ws[vo] + 0.2f * pre;
            v_ws[vo] = vn;
            float h = vn > 0.f ? vn : 0.f;
            allh[(size_t)b*HDIM + i] = h;
            short hh = f2bf(h);
            hwh[b*HDIM + i] = hh;
            hwl[b*HDIM + i] = f2bf(h - bf2f(hh));
            if (j == 2) outp[(size_t)b*HDIM + i] = (i < NE) ? h : 0.f;
        }
    }
}

/* ================= fp32 fallback path (round-1 kernel, kept for small ws_size) ================= */
__global__ __launch_bounds__(256) void ei_init(const float* __restrict__ h0,
                                               float* __restrict__ out,
                                               float* __restrict__ v_ws) {
    int idx = blockIdx.x * 256 + threadIdx.x;
    int l = idx >> 16, r = idx & 0xFFFF;
    out[OUT0_SZ + (size_t)l*ALLH_L + r] = h0[r];
    v_ws[idx] = 0.0f;
}

__global__ __launch_bounds__(256) void ei_stage(
    const float* __restrict__ xin, const float* __restrict__ Win0,
    const float* __restrict__ Win1, const float* __restrict__ Win2,
    const float* __restrict__ Wrec, const float* __restrict__ bias,
    float* __restrict__ out, float* __restrict__ v_ws, int s)
{
    const int j  = blockIdx.x >> 6;
    const int cb = blockIdx.x & 63;
    const int t  = s - j;
    if (t < 0 || t >= T_STEPS) return;
    float* all_h = out + OUT0_SZ;
    const float* Win = (j == 0) ? Win0 : (j == 1 ? Win1 : Win2);
    const int K1 = (j == 0) ? INDIM : HDIM;
    const float* Wr = Wrec + j * HDIM * HDIM;
    const float* ffp; int ffld;
    if (j == 0) { ffp = xin + (size_t)t * BATCH * INDIM; ffld = INDIM; }
    else        { ffp = all_h + ((size_t)(j - 1) * 129 + (t + 1)) * BH; ffld = HDIM; }
    const float* hj = all_h + ((size_t)j * 129 + t) * BH;
    __shared__ float Xs[64][68];
    __shared__ float Ws[16][65];
    const int tx = threadIdx.x;
    const int i_loc = tx & 15;
    const int b0 = (tx >> 4) * 4;
    const int i0 = cb * 16;
    float acc0 = 0.f, acc1 = 0.f, acc2 = 0.f, acc3 = 0.f;
    const int nch_ff = K1 >> 6;
    const int nch = nch_ff + (HDIM >> 6);
    for (int ch = 0; ch < nch; ++ch) {
        const bool ff = ch < nch_ff;
        const int kb = ff ? (ch << 6) : ((ch - nch_ff) << 6);
        __syncthreads();
        #pragma unroll
        for (int it = 0; it < 16; ++it) {
            int idx = it * 256 + tx;
            int bl = idx >> 6, kl = idx & 63, k = kb + kl;
            float v;
            if (ff) { v = ffp[bl * ffld + k]; if (j != 0 && k >= NE) v = 0.0f; }
            else    { v = hj[bl * HDIM + k];  if (k >= NE) v = -v; }
            Xs[kl][bl] = v;
        }
        const float* W = ff ? Win : Wr;
        const int ldw = ff ? K1 : HDIM;
        #pragma unroll
        for (int it = 0; it < 4; ++it) {
            int idx = it * 256 + tx;
            int il = idx >> 6, kl = idx & 63;
            Ws[il][kl] = fabsf(W[(i0 + il) * ldw + kb + kl]);
        }
        __syncthreads();
        #pragma unroll
        for (int kk = 0; kk < 64; ++kk) {
            const float w = Ws[i_loc][kk];
            const float4 x4 = *reinterpret_cast<const float4*>(&Xs[kk][b0]);
            acc0 = fmaf(x4.x, w, acc0); acc1 = fmaf(x4.y, w, acc1);
            acc2 = fmaf(x4.z, w, acc2); acc3 = fmaf(x4.w, w, acc3);
        }
    }
    const int i = i0 + i_loc;
    const float bj = bias[j * HDIM + i];
    float accs[4] = {acc0, acc1, acc2, acc3};
    #pragma unroll
    for (int r = 0; r < 4; ++r) {
        const int b = b0 + r;
        const float pre = accs[r] + bj;
        float* vp = v_ws + ((size_t)j * BATCH + b) * HDIM + i;
        const float vn = 0.8f * (*vp) + 0.2f * pre;
        *vp = vn;
        const float h = vn > 0.f ? vn : 0.f;
        all_h[((size_t)j * 129 + (t + 1)) * BH + b * HDIM + i] = h;
        if (j == 2) out[((size_t)t * BATCH + b) * HDIM + i] = (i < NE) ? h : 0.f;
    }
}

extern "C" void kernel_launch(void* const* d_in, const int* in_sizes, int n_in,
                              void* d_out, int out_size, void* d_ws, size_t ws_size,
                              hipStream_t stream) {
    const float* xin  = (const float*)d_in[0];
    const float* h0   = (const float*)d_in[1];
    const float* Win0 = (const float*)d_in[2];
    const float* Win1 = (const float*)d_in[3];
    const float* Win2 = (const float*)d_in[4];
    const float* Wrec = (const float*)d_in[5];
    const float* bias = (const float*)d_in[6];
    float* out  = (float*)d_out;
    char* ws    = (char*)d_ws;

    if (ws_size >= (size_t)WS_NEED) {
        float* v_ws = (float*)(ws + WS_V);
        short* hs   = (short*)(ws + WS_HS);
        short* xhi  = (short*)(ws + WS_XHI);
        short* xlo  = (short*)(ws + WS_XLO);
        short* wf   = (short*)(ws + WS_WF);
        hipLaunchKernelGGL(ei_prep_w, dim3(2816), dim3(256), 0, stream,
                           Win0, Win1, Win2, Wrec, wf);
        hipLaunchKernelGGL(ei_prep_x, dim3(4096), dim3(256), 0, stream, xin, xhi, xlo);
        hipLaunchKernelGGL(ei_init2, dim3(768), dim3(256), 0, stream, h0, out, v_ws, hs);
        for (int s = 0; s < T_STEPS + 2; ++s)
            hipLaunchKernelGGL(ei_stage2, dim3(96), dim3(256), 0, stream,
                               xhi, xlo, wf, bias, out, v_ws, hs, s);
    } else {
        float* v_ws = (float*)ws;
        hipLaunchKernelGGL(ei_init, dim3(768), dim3(256), 0, stream, h0, out, v_ws);
        for (int s = 0; s < T_STEPS + 2; ++s)
            hipLaunchKernelGGL(ei_stage, dim3(192), dim3(256), 0, stream,
                               xin, Win0, Win1, Win2, Wrec, bias, out, v_ws, s);
    }
}

// Round 3
// 3433.127 us; speedup vs baseline: 7.8620x; 1.1512x over previous
//
#include <hip/hip_runtime.h>

#define T_STEPS 128
#define BATCH   64
#define INDIM   512
#define HDIM    1024
#define NE      819
#define OUT0_SZ (T_STEPS*BATCH*HDIM)
#define BH      (BATCH*HDIM)          /* 65536 */
#define ALLH_L  (129*BH)

/* ---- workspace layout (bytes) ---- */
#define WS_V    0                     /* fp32 v-state: 3*64*1024*4 = 786432 */
#define WS_HS   786432                /* bf16 h split, 2 parities: 2*3*2*65536*2 = 1572864 */
#define WS_XHI  2359296               /* bf16 x hi: 4194304*2 */
#define WS_XLO  10747904              /* bf16 x lo */
#define WS_WF   19136512              /* bf16 weight fragments: 11534336*2 */
#define WS_NEED 42205184
#define HS_PAR  393216                /* elements per parity */
#define HS_LAY  131072

typedef short bf16x8 __attribute__((ext_vector_type(8)));
typedef short s16x4  __attribute__((ext_vector_type(4)));
typedef float f32x4  __attribute__((ext_vector_type(4)));

__device__ __forceinline__ short f2bf(float f){
    unsigned u = __float_as_uint(f);
    u += 0x7FFF + ((u >> 16) & 1);           /* RNE */
    return (short)(u >> 16);
}
__device__ __forceinline__ float bf2f(short s){
    return __uint_as_float(((unsigned)(unsigned short)s) << 16);
}

/* ============ one-time prep: weights -> |.|*sign*emask, split hi/lo, frag-swizzled ============ */
/* layout per layer: [it(64)][kb(nkb)][hi/lo][lane(64)][8] bf16; L0 nkb=48, L1/2 nkb=64 */
__global__ __launch_bounds__(256) void ei_prep_w(const float* __restrict__ Win0,
        const float* __restrict__ Win1, const float* __restrict__ Win2,
        const float* __restrict__ Wrec, short* __restrict__ wf){
    int gid = blockIdx.x * 256 + threadIdx.x;      /* 0 .. 720895 */
    int j, local, nkb, kff; const float* Win; short* base;
    if (gid < 196608)      { j=0; local=gid;        nkb=48; kff=512;  Win=Win0; base=wf; }
    else if (gid < 458752) { j=1; local=gid-196608; nkb=64; kff=1024; Win=Win1; base=wf+3145728; }
    else                   { j=2; local=gid-458752; nkb=64; kff=1024; Win=Win2; base=wf+7340032; }
    int lane = local & 63;
    int fi   = local >> 6;                         /* it*nkb + kb */
    int kb   = fi % nkb;
    int it   = fi / nkb;
    int i    = it*16 + (lane & 15);
    int k0   = kb*32 + ((lane >> 4) << 3);
    const float* wrec_row = Wrec + ((size_t)j*HDIM + i)*HDIM;
    bf16x8 hv, lv;
    #pragma unroll
    for (int e = 0; e < 8; ++e){
        int k = k0 + e;
        float w;
        if (k < kff){
            w = fabsf(Win[(size_t)i*kff + k]);
            if (j != 0 && k >= NE) w = 0.f;        /* e_mask folded into ff weights */
        } else {
            int kr = k - kff;
            w = fabsf(wrec_row[kr]);
            if (kr >= NE) w = -w;                  /* Dale sign folded */
        }
        short h = f2bf(w);
        hv[e] = h;
        lv[e] = f2bf(w - bf2f(h));
    }
    short* dst = base + (size_t)fi*1024 + lane*8;
    *(bf16x8*)dst         = hv;
    *(bf16x8*)(dst + 512) = lv;
}

/* ============ one-time prep: split all inputs x into bf16 hi/lo planes ============ */
__global__ __launch_bounds__(256) void ei_prep_x(const float* __restrict__ x,
        short* __restrict__ xhi, short* __restrict__ xlo){
    int gid = blockIdx.x * 256 + threadIdx.x;      /* 0 .. 1048575, 4 elems each */
    float4 v = ((const float4*)x)[gid];
    s16x4 hv, lv;
    float f[4] = {v.x, v.y, v.z, v.w};
    #pragma unroll
    for (int e = 0; e < 4; ++e){
        short h = f2bf(f[e]);
        hv[e] = h; lv[e] = f2bf(f[e] - bf2f(h));
    }
    ((s16x4*)xhi)[gid] = hv;
    ((s16x4*)xlo)[gid] = lv;
}

/* ============ init: all_h[l][0]=h0, v=0, h-split both parities ============ */
__global__ __launch_bounds__(256) void ei_init2(const float* __restrict__ h0,
        float* __restrict__ out, float* __restrict__ v_ws, short* __restrict__ hs){
    int idx = blockIdx.x * 256 + threadIdx.x;      /* 0 .. 196607 */
    int l = idx >> 16, r = idx & 0xFFFF;
    float h = h0[r];
    out[OUT0_SZ + (size_t)l*ALLH_L + r] = h;
    v_ws[idx] = 0.f;
    short hh = f2bf(h), hl = f2bf(h - bf2f(hh));
    hs[          l*HS_LAY + r]         = hh;
    hs[          l*HS_LAY + 65536 + r] = hl;
    hs[HS_PAR +  l*HS_LAY + r]         = hh;
    hs[HS_PAR +  l*HS_LAY + 65536 + r] = hl;
}

/* ============ skewed step v3: weights read ONCE (P_b=1).
   grid = 192 blocks = (j, it-strip of 16 cols); 4 waves = 4 K-slices;
   each wave computes all 64 batch rows (4 bt MFMA tiles) for its K-slice;
   LDS partial reduce across the 4 K-slices, fused epilogue. ============ */
__global__ __launch_bounds__(256) void ei_stage3(
        const short* __restrict__ xhi, const short* __restrict__ xlo,
        const short* __restrict__ wf,  const float* __restrict__ bias,
        float* __restrict__ out, float* __restrict__ v_ws,
        short* __restrict__ hs, int s)
{
    int j = blockIdx.x >> 6;
    int t = s - j;
    if (t < 0 || t >= T_STEPS) return;
    int it = blockIdx.x & 63;
    int wv = threadIdx.x >> 6, lane = threadIdx.x & 63;
    int par_r = (s - 1) & 1, par_w = s & 1;

    int nkb, nkff, ldff;
    const short *ffh, *ffl;
    if (j == 0){
        nkb = 48; nkff = 16; ldff = INDIM;
        ffh = xhi + (size_t)t*BATCH*INDIM;
        ffl = xlo + (size_t)t*BATCH*INDIM;
    } else {
        nkb = 64; nkff = 32; ldff = HDIM;
        const short* b0 = hs + par_r*HS_PAR + (j-1)*HS_LAY;
        ffh = b0; ffl = b0 + 65536;
    }
    const short* rbase = hs + par_r*HS_PAR + j*HS_LAY;

    const int l15  = lane & 15;
    const int kloc = (lane >> 4) << 3;
    const short* wfj = wf + (j==0 ? 0 : (j==1 ? 3145728 : 7340032));
    const short* wp  = wfj + (size_t)it*nkb*1024 + lane*8;

    const int nkw = nkb >> 2;          /* kb per wave: 12 (L0) or 16 */
    const int kb0 = wv * nkw;

    f32x4 acc[4] = {{0.f,0.f,0.f,0.f},{0.f,0.f,0.f,0.f},
                    {0.f,0.f,0.f,0.f},{0.f,0.f,0.f,0.f}};

    #pragma unroll 4
    for (int kk = 0; kk < nkw; ++kk){
        int kb = kb0 + kk;
        int isff = (kb < nkff);
        int ld   = isff ? ldff : HDIM;
        int ko   = isff ? kb*32 : (kb - nkff)*32;
        const short* pah = (isff ? ffh : rbase)           + (size_t)l15*ld + ko + kloc;
        const short* pal = (isff ? ffl : (rbase + 65536)) + (size_t)l15*ld + ko + kloc;
        bf16x8 ah[4], al[4];
        #pragma unroll
        for (int bt = 0; bt < 4; ++bt){
            ah[bt] = *(const bf16x8*)(pah + (size_t)bt*16*ld);
            al[bt] = *(const bf16x8*)(pal + (size_t)bt*16*ld);
        }
        const short* w0 = wp + (size_t)kb*1024;
        bf16x8 bh = *(const bf16x8*)w0;
        bf16x8 bl = *(const bf16x8*)(w0 + 512);
        #pragma unroll
        for (int bt = 0; bt < 4; ++bt)
            acc[bt] = __builtin_amdgcn_mfma_f32_16x16x32_bf16(ah[bt], bh, acc[bt], 0,0,0);
        #pragma unroll
        for (int bt = 0; bt < 4; ++bt)
            acc[bt] = __builtin_amdgcn_mfma_f32_16x16x32_bf16(al[bt], bh, acc[bt], 0,0,0);
        #pragma unroll
        for (int bt = 0; bt < 4; ++bt)
            acc[bt] = __builtin_amdgcn_mfma_f32_16x16x32_bf16(ah[bt], bl, acc[bt], 0,0,0);
    }

    /* partials -> LDS. C/D layout: col=lane&15, row=(lane>>4)*4+r [m89] */
    __shared__ float psum[4][64][16];
    const int r0 = (lane >> 4) * 4;
    #pragma unroll
    for (int bt = 0; bt < 4; ++bt)
        #pragma unroll
        for (int r = 0; r < 4; ++r)
            psum[wv][bt*16 + r0 + r][l15] = acc[bt][r];
    __syncthreads();

    /* reduce 4 K-slices + fused epilogue; thread -> (b, 4 consecutive i) */
    int tx  = threadIdx.x;
    int b   = tx >> 2;
    int il0 = (tx & 3) * 4;
    float* allh = out + OUT0_SZ + ((size_t)(j*129 + t + 1))*BH;
    float* outp = out + (size_t)t*BH;
    short* hwh  = hs + par_w*HS_PAR + j*HS_LAY;
    short* hwl  = hwh + 65536;
    #pragma unroll
    for (int e = 0; e < 4; ++e){
        int il = il0 + e;
        float sum = psum[0][b][il] + psum[1][b][il] + psum[2][b][il] + psum[3][b][il];
        int i = it*16 + il;
        float pre = sum + bias[j*HDIM + i];
        size_t vo = ((size_t)j*BATCH + b)*HDIM + i;
        float vn = 0.8f * v_ws[vo] + 0.2f * pre;
        v_ws[vo] = vn;
        float h = vn > 0.f ? vn : 0.f;
        allh[(size_t)b*HDIM + i] = h;
        short hh = f2bf(h);
        hwh[b*HDIM + i] = hh;
        hwl[b*HDIM + i] = f2bf(h - bf2f(hh));
        if (j == 2) outp[(size_t)b*HDIM + i] = (i < NE) ? h : 0.f;
    }
}

/* ================= fp32 fallback path (kept for small ws_size) ================= */
__global__ __launch_bounds__(256) void ei_init(const float* __restrict__ h0,
                                               float* __restrict__ out,
                                               float* __restrict__ v_ws) {
    int idx = blockIdx.x * 256 + threadIdx.x;
    int l = idx >> 16, r = idx & 0xFFFF;
    out[OUT0_SZ + (size_t)l*ALLH_L + r] = h0[r];
    v_ws[idx] = 0.0f;
}

__global__ __launch_bounds__(256) void ei_stage(
    const float* __restrict__ xin, const float* __restrict__ Win0,
    const float* __restrict__ Win1, const float* __restrict__ Win2,
    const float* __restrict__ Wrec, const float* __restrict__ bias,
    float* __restrict__ out, float* __restrict__ v_ws, int s)
{
    const int j  = blockIdx.x >> 6;
    const int cb = blockIdx.x & 63;
    const int t  = s - j;
    if (t < 0 || t >= T_STEPS) return;
    float* all_h = out + OUT0_SZ;
    const float* Win = (j == 0) ? Win0 : (j == 1 ? Win1 : Win2);
    const int K1 = (j == 0) ? INDIM : HDIM;
    const float* Wr = Wrec + j * HDIM * HDIM;
    const float* ffp; int ffld;
    if (j == 0) { ffp = xin + (size_t)t * BATCH * INDIM; ffld = INDIM; }
    else        { ffp = all_h + ((size_t)(j - 1) * 129 + (t + 1)) * BH; ffld = HDIM; }
    const float* hj = all_h + ((size_t)j * 129 + t) * BH;
    __shared__ float Xs[64][68];
    __shared__ float Ws[16][65];
    const int tx = threadIdx.x;
    const int i_loc = tx & 15;
    const int b0 = (tx >> 4) * 4;
    const int i0 = cb * 16;
    float acc0 = 0.f, acc1 = 0.f, acc2 = 0.f, acc3 = 0.f;
    const int nch_ff = K1 >> 6;
    const int nch = nch_ff + (HDIM >> 6);
    for (int ch = 0; ch < nch; ++ch) {
        const bool ff = ch < nch_ff;
        const int kb = ff ? (ch << 6) : ((ch - nch_ff) << 6);
        __syncthreads();
        #pragma unroll
        for (int itr = 0; itr < 16; ++itr) {
            int idx = itr * 256 + tx;
            int bl = idx >> 6, kl = idx & 63, k = kb + kl;
            float v;
            if (ff) { v = ffp[bl * ffld + k]; if (j != 0 && k >= NE) v = 0.0f; }
            else    { v = hj[bl * HDIM + k];  if (k >= NE) v = -v; }
            Xs[kl][bl] = v;
        }
        const float* W = ff ? Win : Wr;
        const int ldw = ff ? K1 : HDIM;
        #pragma unroll
        for (int itr = 0; itr < 4; ++itr) {
            int idx = itr * 256 + tx;
            int il = idx >> 6, kl = idx & 63;
            Ws[il][kl] = fabsf(W[(i0 + il) * ldw + kb + kl]);
        }
        __syncthreads();
        #pragma unroll
        for (int kk = 0; kk < 64; ++kk) {
            const float w = Ws[i_loc][kk];
            const float4 x4 = *reinterpret_cast<const float4*>(&Xs[kk][b0]);
            acc0 = fmaf(x4.x, w, acc0); acc1 = fmaf(x4.y, w, acc1);
            acc2 = fmaf(x4.z, w, acc2); acc3 = fmaf(x4.w, w, acc3);
        }
    }
    const int i = i0 + i_loc;
    const float bj = bias[j * HDIM + i];
    float accs[4] = {acc0, acc1, acc2, acc3};
    #pragma unroll
    for (int r = 0; r < 4; ++r) {
        const int b = b0 + r;
        const float pre = accs[r] + bj;
        float* vp = v_ws + ((size_t)j * BATCH + b) * HDIM + i;
        const float vn = 0.8f * (*vp) + 0.2f * pre;
        *vp = vn;
        const float h = vn > 0.f ? vn : 0.f;
        all_h[((size_t)j * 129 + (t + 1)) * BH + b * HDIM + i] = h;
        if (j == 2) out[((size_t)t * BATCH + b) * HDIM + i] = (i < NE) ? h : 0.f;
    }
}

extern "C" void kernel_launch(void* const* d_in, const int* in_sizes, int n_in,
                              void* d_out, int out_size, void* d_ws, size_t ws_size,
                              hipStream_t stream) {
    const float* xin  = (const float*)d_in[0];
    const float* h0   = (const float*)d_in[1];
    const float* Win0 = (const float*)d_in[2];
    const float* Win1 = (const float*)d_in[3];
    const float* Win2 = (const float*)d_in[4];
    const float* Wrec = (const float*)d_in[5];
    const float* bias = (const float*)d_in[6];
    float* out  = (float*)d_out;
    char* ws    = (char*)d_ws;

    if (ws_size >= (size_t)WS_NEED) {
        float* v_ws = (float*)(ws + WS_V);
        short* hs   = (short*)(ws + WS_HS);
        short* xhi  = (short*)(ws + WS_XHI);
        short* xlo  = (short*)(ws + WS_XLO);
        short* wf   = (short*)(ws + WS_WF);
        hipLaunchKernelGGL(ei_prep_w, dim3(2816), dim3(256), 0, stream,
                           Win0, Win1, Win2, Wrec, wf);
        hipLaunchKernelGGL(ei_prep_x, dim3(4096), dim3(256), 0, stream, xin, xhi, xlo);
        hipLaunchKernelGGL(ei_init2, dim3(768), dim3(256), 0, stream, h0, out, v_ws, hs);
        for (int s = 0; s < T_STEPS + 2; ++s)
            hipLaunchKernelGGL(ei_stage3, dim3(192), dim3(256), 0, stream,
                               xhi, xlo, wf, bias, out, v_ws, hs, s);
    } else {
        float* v_ws = (float*)ws;
        hipLaunchKernelGGL(ei_init, dim3(768), dim3(256), 0, stream, h0, out, v_ws);
        for (int s = 0; s < T_STEPS + 2; ++s)
            hipLaunchKernelGGL(ei_stage, dim3(192), dim3(256), 0, stream,
                               xin, Win0, Win1, Win2, Wrec, bias, out, v_ws, s);
    }
}

// Round 5
// 1997.293 us; speedup vs baseline: 13.5139x; 1.7189x over previous
//
#include <hip/hip_runtime.h>

#define T_STEPS 128
#define BATCH   64
#define INDIM   512
#define HDIM    1024
#define NE      819
#define OUT0_SZ (T_STEPS*BATCH*HDIM)
#define BH      (BATCH*HDIM)          /* 65536 */
#define ALLH_L  (129*BH)

#define HS_LAY   131072               /* shorts per (parity,layer): 2 planes x 65536 */
#define HS_PAR   393216               /* shorts per parity (3 layers) */
#define HF_COPY  786432               /* shorts per replica (2 parities) */
#define XF_T     65536                /* shorts per timestep of x-frags: hi 32768 + lo 32768 */

typedef short bf16x8 __attribute__((ext_vector_type(8)));
typedef float f32x4  __attribute__((ext_vector_type(4)));

__device__ __forceinline__ short f2bf(float f){
    unsigned u = __float_as_uint(f);
    u += 0x7FFF + ((u >> 16) & 1);           /* RNE */
    return (short)(u >> 16);
}
__device__ __forceinline__ float bf2f(short s){
    return __uint_as_float(((unsigned)(unsigned short)s) << 16);
}

/* ============ one-time prep: weights -> |.|*sign*emask, split hi/lo, frag-swizzled ============ */
/* layout per layer: [it(64)][kb(nkb)][hi(512)|lo(512)] shorts; L0 nkb=48, L1/2 nkb=64 */
__global__ __launch_bounds__(256) void ei_prep_w(const float* __restrict__ Win0,
        const float* __restrict__ Win1, const float* __restrict__ Win2,
        const float* __restrict__ Wrec, short* __restrict__ wf){
    int gid = blockIdx.x * 256 + threadIdx.x;      /* 0 .. 720895 */
    int j, local, nkb, kff; const float* Win; short* base;
    if (gid < 196608)      { j=0; local=gid;        nkb=48; kff=512;  Win=Win0; base=wf; }
    else if (gid < 458752) { j=1; local=gid-196608; nkb=64; kff=1024; Win=Win1; base=wf+3145728; }
    else                   { j=2; local=gid-458752; nkb=64; kff=1024; Win=Win2; base=wf+7340032; }
    int lane = local & 63;
    int fi   = local >> 6;                         /* it*nkb + kb */
    int kb   = fi % nkb;
    int it   = fi / nkb;
    int i    = it*16 + (lane & 15);
    int k0   = kb*32 + ((lane >> 4) << 3);
    const float* wrec_row = Wrec + ((size_t)j*HDIM + i)*HDIM;
    bf16x8 hv, lv;
    #pragma unroll
    for (int e = 0; e < 8; ++e){
        int k = k0 + e;
        float w;
        if (k < kff){
            w = fabsf(Win[(size_t)i*kff + k]);
            if (j != 0 && k >= NE) w = 0.f;        /* e_mask folded into ff weights */
        } else {
            int kr = k - kff;
            w = fabsf(wrec_row[kr]);
            if (kr >= NE) w = -w;                  /* Dale sign folded */
        }
        short h = f2bf(w);
        hv[e] = h;
        lv[e] = f2bf(w - bf2f(h));
    }
    short* dst = base + (size_t)fi*1024 + lane*8;
    *(bf16x8*)dst         = hv;
    *(bf16x8*)(dst + 512) = lv;
}

/* ============ one-time prep: x -> A-frag layout [t][plane][kb(16)][bt(4)][lane(64)][8] ============ */
/* per t: hi plane [0,32768) shorts, lo plane [32768,65536) */
__global__ __launch_bounds__(256) void ei_prep_xf(const float* __restrict__ x,
        short* __restrict__ xf){
    int gid = blockIdx.x * 256 + threadIdx.x;      /* 0 .. 524287 */
    int lane = gid & 63;
    int bt   = (gid >> 6) & 3;
    int kb   = (gid >> 8) & 15;
    int t    = gid >> 12;
    int b = bt*16 + (lane & 15);
    int k = kb*32 + ((lane >> 4) << 3);
    const float* src = x + ((size_t)t*BATCH + b)*INDIM + k;
    float4 v0 = *(const float4*)src;
    float4 v1 = *(const float4*)(src + 4);
    float f[8] = {v0.x,v0.y,v0.z,v0.w,v1.x,v1.y,v1.z,v1.w};
    bf16x8 hv, lv;
    #pragma unroll
    for (int e = 0; e < 8; ++e){
        short h = f2bf(f[e]);
        hv[e] = h; lv[e] = f2bf(f[e] - bf2f(h));
    }
    short* dst = xf + (size_t)t*XF_T + (((size_t)(kb*4 + bt)) << 9) + lane*8;
    *(bf16x8*)dst            = hv;
    *(bf16x8*)(dst + 32768)  = lv;
}

/* ============ init: all_h[l][0]=h0, v=0, h-frags (all replicas, both parities) ============ */
__global__ __launch_bounds__(256) void ei_init3(const float* __restrict__ h0,
        float* __restrict__ out, float* __restrict__ v_ws, short* __restrict__ hf, int rep){
    int idx = blockIdx.x * 256 + threadIdx.x;      /* 0 .. 196607 */
    int l = idx >> 16, r = idx & 0xFFFF;
    float h = h0[r];
    out[OUT0_SZ + (size_t)l*ALLH_L + r] = h;
    v_ws[idx] = 0.f;
    if (idx < 24576){
        int lane = idx & 63, bt = (idx >> 6) & 3, kb = (idx >> 8) & 31, j = idx >> 13;
        int b = bt*16 + (lane & 15);
        int k = kb*32 + ((lane >> 4) << 3);
        const float* src = h0 + (size_t)b*HDIM + k;
        float4 v0 = *(const float4*)src;
        float4 v1 = *(const float4*)(src + 4);
        float f[8] = {v0.x,v0.y,v0.z,v0.w,v1.x,v1.y,v1.z,v1.w};
        bf16x8 hv, lv;
        #pragma unroll
        for (int e = 0; e < 8; ++e){
            short hh = f2bf(f[e]);
            hv[e] = hh; lv[e] = f2bf(f[e] - bf2f(hh));
        }
        size_t off = (((size_t)(kb*4 + bt)) << 9) + lane*8;
        for (int c = 0; c < rep; ++c){
            short* b0 = hf + (size_t)c*HF_COPY + (size_t)j*HS_LAY + off;
            *(bf16x8*)b0           = hv;
            *(bf16x8*)(b0 + 65536) = lv;
            short* b1 = b0 + HS_PAR;
            *(bf16x8*)b1           = hv;
            *(bf16x8*)(b1 + 65536) = lv;
        }
    }
}

/* ============ K-loop body: fully frag-coalesced streams, 3-MFMA split ============ */
/* FFLO = lo-plane offset of the feedforward frag buffer (32768 for x, 65536 for h) */
template<int NKB, int NKFF, int FFLO>
__device__ __forceinline__ void stage_body(
        const short* __restrict__ pff, const short* __restrict__ prec,
        const short* __restrict__ wp, int kb0, int laneo, f32x4 acc[4])
{
    #pragma unroll 2
    for (int kk = 0; kk < (NKB >> 3); ++kk){
        int kb = kb0 + kk;
        const bool isff = (kb < NKFF);
        const short* pa = isff ? (pff + ((size_t)kb << 11))
                               : (prec + ((size_t)(kb - NKFF) << 11));
        const int lo = isff ? FFLO : 65536;
        const short* w0 = wp + ((size_t)kb << 10);
        bf16x8 bh = *(const bf16x8*)w0;
        bf16x8 bl = *(const bf16x8*)(w0 + 512);
        bf16x8 ah[4], al[4];
        #pragma unroll
        for (int bt = 0; bt < 4; ++bt){
            ah[bt] = *(const bf16x8*)(pa + (bt << 9) + laneo);
            al[bt] = *(const bf16x8*)(pa + lo + (bt << 9) + laneo);
        }
        #pragma unroll
        for (int bt = 0; bt < 4; ++bt)
            acc[bt] = __builtin_amdgcn_mfma_f32_16x16x32_bf16(ah[bt], bh, acc[bt], 0,0,0);
        #pragma unroll
        for (int bt = 0; bt < 4; ++bt)
            acc[bt] = __builtin_amdgcn_mfma_f32_16x16x32_bf16(al[bt], bh, acc[bt], 0,0,0);
        #pragma unroll
        for (int bt = 0; bt < 4; ++bt)
            acc[bt] = __builtin_amdgcn_mfma_f32_16x16x32_bf16(ah[bt], bl, acc[bt], 0,0,0);
    }
}

/* ============ skewed step v4: 192 blocks x 512 thr (8 waves = 8 K-slices) ============ */
__global__ __launch_bounds__(512, 2) void ei_stage4(
        const short* __restrict__ xf, const short* __restrict__ wf,
        const float* __restrict__ bias, float* __restrict__ out,
        float* __restrict__ v_ws, short* __restrict__ hf, int s, int rep)
{
    int j = blockIdx.x >> 6;
    int t = s - j;
    if (t < 0 || t >= T_STEPS) return;
    int it = blockIdx.x & 63;
    int wv = threadIdx.x >> 6, lane = threadIdx.x & 63;
    int laneo = lane * 8;
    int par_r = (s - 1) & 1, par_w = s & 1;
    int rc = (rep == 8) ? (blockIdx.x & 7) : 0;
    const short* hfr = hf + (size_t)rc*HF_COPY + (size_t)par_r*HS_PAR;
    const short* prec = hfr + (size_t)j*HS_LAY;

    f32x4 acc[4] = {{0.f,0.f,0.f,0.f},{0.f,0.f,0.f,0.f},
                    {0.f,0.f,0.f,0.f},{0.f,0.f,0.f,0.f}};

    if (j == 0){
        const short* pff = xf + (size_t)t*XF_T;
        const short* wp  = wf + ((size_t)it*48)*1024 + laneo;
        stage_body<48,16,32768>(pff, prec, wp, wv*6, laneo, acc);
    } else if (j == 1){
        const short* pff = hfr;                       /* layer 0 h-frags */
        const short* wp  = wf + 3145728 + ((size_t)it*64)*1024 + laneo;
        stage_body<64,32,65536>(pff, prec, wp, wv*8, laneo, acc);
    } else {
        const short* pff = hfr + HS_LAY;              /* layer 1 h-frags */
        const short* wp  = wf + 7340032 + ((size_t)it*64)*1024 + laneo;
        stage_body<64,32,65536>(pff, prec, wp, wv*8, laneo, acc);
    }

    /* partials -> LDS. C/D layout: col=lane&15, row=(lane>>4)*4+r [m89] */
    __shared__ float psum[8][64][17];
    {
        int r0 = (lane >> 4) << 2, l15 = lane & 15;
        #pragma unroll
        for (int bt = 0; bt < 4; ++bt)
            #pragma unroll
            for (int r = 0; r < 4; ++r)
                psum[wv][bt*16 + r0 + r][l15] = acc[bt][r];
    }
    __syncthreads();

    /* reduce 8 K-slices + fused epilogue; thread -> (b, 2 consecutive i) */
    int tx  = threadIdx.x;
    int b   = tx >> 3;
    int il0 = (tx & 7) << 1;
    float* allh = out + OUT0_SZ + ((size_t)(j*129 + t + 1))*BH;
    float* outp = out + (size_t)t*BH;
    short* hww  = hf + (size_t)par_w*HS_PAR + (size_t)j*HS_LAY;   /* replica 0 */
    #pragma unroll
    for (int e = 0; e < 2; ++e){
        int il = il0 + e;
        float sum = psum[0][b][il] + psum[1][b][il] + psum[2][b][il] + psum[3][b][il]
                  + psum[4][b][il] + psum[5][b][il] + psum[6][b][il] + psum[7][b][il];
        int i = it*16 + il;
        float pre = sum + bias[j*HDIM + i];
        size_t vo = ((size_t)j*BATCH + b)*HDIM + i;
        float vn = 0.8f * v_ws[vo] + 0.2f * pre;
        v_ws[vo] = vn;
        float h = vn > 0.f ? vn : 0.f;
        allh[(size_t)b*HDIM + i] = h;
        short hh = f2bf(h), hl = f2bf(h - bf2f(hh));
        int kb  = i >> 5, btw = b >> 4;
        int lnw = (b & 15) + (((i >> 3) & 3) << 4);
        size_t off = (((size_t)(kb*4 + btw)) << 9) + lnw*8 + (i & 7);
        for (int c = 0; c < rep; ++c){
            short* d = hww + (size_t)c*HF_COPY + off;
            d[0]     = hh;
            d[65536] = hl;
        }
        if (j == 2) outp[(size_t)b*HDIM + i] = (i < NE) ? h : 0.f;
    }
}

/* ================= fp32 fallback path (kept for small ws_size) ================= */
__global__ __launch_bounds__(256) void ei_init(const float* __restrict__ h0,
                                               float* __restrict__ out,
                                               float* __restrict__ v_ws) {
    int idx = blockIdx.x * 256 + threadIdx.x;
    int l = idx >> 16, r = idx & 0xFFFF;
    out[OUT0_SZ + (size_t)l*ALLH_L + r] = h0[r];
    v_ws[idx] = 0.0f;
}

__global__ __launch_bounds__(256) void ei_stage(
    const float* __restrict__ xin, const float* __restrict__ Win0,
    const float* __restrict__ Win1, const float* __restrict__ Win2,
    const float* __restrict__ Wrec, const float* __restrict__ bias,
    float* __restrict__ out, float* __restrict__ v_ws, int s)
{
    const int j  = blockIdx.x >> 6;
    const int cb = blockIdx.x & 63;
    const int t  = s - j;
    if (t < 0 || t >= T_STEPS) return;
    float* all_h = out + OUT0_SZ;
    const float* Win = (j == 0) ? Win0 : (j == 1 ? Win1 : Win2);
    const int K1 = (j == 0) ? INDIM : HDIM;
    const float* Wr = Wrec + j * HDIM * HDIM;
    const float* ffp; int ffld;
    if (j == 0) { ffp = xin + (size_t)t * BATCH * INDIM; ffld = INDIM; }
    else        { ffp = all_h + ((size_t)(j - 1) * 129 + (t + 1)) * BH; ffld = HDIM; }
    const float* hj = all_h + ((size_t)j * 129 + t) * BH;
    __shared__ float Xs[64][68];
    __shared__ float Ws[16][65];
    const int tx = threadIdx.x;
    const int i_loc = tx & 15;
    const int b0 = (tx >> 4) * 4;
    const int i0 = cb * 16;
    float acc0 = 0.f, acc1 = 0.f, acc2 = 0.f, acc3 = 0.f;
    const int nch_ff = K1 >> 6;
    const int nch = nch_ff + (HDIM >> 6);
    for (int ch = 0; ch < nch; ++ch) {
        const bool ff = ch < nch_ff;
        const int kb = ff ? (ch << 6) : ((ch - nch_ff) << 6);
        __syncthreads();
        #pragma unroll
        for (int itr = 0; itr < 16; ++itr) {
            int idx = itr * 256 + tx;
            int bl = idx >> 6, kl = idx & 63, k = kb + kl;
            float v;
            if (ff) { v = ffp[bl * ffld + k]; if (j != 0 && k >= NE) v = 0.0f; }
            else    { v = hj[bl * HDIM + k];  if (k >= NE) v = -v; }
            Xs[kl][bl] = v;
        }
        const float* W = ff ? Win : Wr;
        const int ldw = ff ? K1 : HDIM;
        #pragma unroll
        for (int itr = 0; itr < 4; ++itr) {
            int idx = itr * 256 + tx;
            int il = idx >> 6, kl = idx & 63;
            Ws[il][kl] = fabsf(W[(i0 + il) * ldw + kb + kl]);
        }
        __syncthreads();
        #pragma unroll
        for (int kk = 0; kk < 64; ++kk) {
            const float w = Ws[i_loc][kk];
            const float4 x4 = *reinterpret_cast<const float4*>(&Xs[kk][b0]);
            acc0 = fmaf(x4.x, w, acc0); acc1 = fmaf(x4.y, w, acc1);
            acc2 = fmaf(x4.z, w, acc2); acc3 = fmaf(x4.w, w, acc3);
        }
    }
    const int i = i0 + i_loc;
    const float bj = bias[j * HDIM + i];
    float accs[4] = {acc0, acc1, acc2, acc3};
    #pragma unroll
    for (int r = 0; r < 4; ++r) {
        const int b = b0 + r;
        const float pre = accs[r] + bj;
        float* vp = v_ws + ((size_t)j * BATCH + b) * HDIM + i;
        const float vn = 0.8f * (*vp) + 0.2f * pre;
        *vp = vn;
        const float h = vn > 0.f ? vn : 0.f;
        all_h[((size_t)j * 129 + (t + 1)) * BH + b * HDIM + i] = h;
        if (j == 2) out[((size_t)t * BATCH + b) * HDIM + i] = (i < NE) ? h : 0.f;
    }
}

extern "C" void kernel_launch(void* const* d_in, const int* in_sizes, int n_in,
                              void* d_out, int out_size, void* d_ws, size_t ws_size,
                              hipStream_t stream) {
    const float* xin  = (const float*)d_in[0];
    const float* h0   = (const float*)d_in[1];
    const float* Win0 = (const float*)d_in[2];
    const float* Win1 = (const float*)d_in[3];
    const float* Win2 = (const float*)d_in[4];
    const float* Wrec = (const float*)d_in[5];
    const float* bias = (const float*)d_in[6];
    float* out  = (float*)d_out;
    char* ws    = (char*)d_ws;

    /* layout: v(786432) | hf(rep*1572864) | xf(16777216) | wf(23068672) */
    const size_t need1 = 786432ULL + 1*1572864ULL + 16777216ULL + 23068672ULL; /* 42205184 */
    const size_t need8 = 786432ULL + 8*1572864ULL + 16777216ULL + 23068672ULL; /* 53215232 */

    if (ws_size >= need1) {
        int rep = (ws_size >= need8) ? 8 : 1;
        float* v_ws = (float*)ws;
        short* hf   = (short*)(ws + 786432);
        short* xf   = (short*)(ws + 786432 + (size_t)rep*1572864ULL);
        short* wfp  = (short*)(ws + 786432 + (size_t)rep*1572864ULL + 16777216ULL);
        hipLaunchKernelGGL(ei_prep_w, dim3(2816), dim3(256), 0, stream,
                           Win0, Win1, Win2, Wrec, wfp);
        hipLaunchKernelGGL(ei_prep_xf, dim3(2048), dim3(256), 0, stream, xin, xf);
        hipLaunchKernelGGL(ei_init3, dim3(768), dim3(256), 0, stream, h0, out, v_ws, hf, rep);
        for (int s = 0; s < T_STEPS + 2; ++s)
            hipLaunchKernelGGL(ei_stage4, dim3(192), dim3(512), 0, stream,
                               xf, wfp, bias, out, v_ws, hf, s, rep);
    } else {
        float* v_ws = (float*)ws;
        hipLaunchKernelGGL(ei_init, dim3(768), dim3(256), 0, stream, h0, out, v_ws);
        for (int s = 0; s < T_STEPS + 2; ++s)
            hipLaunchKernelGGL(ei_stage, dim3(192), dim3(256), 0, stream,
                               xin, Win0, Win1, Win2, Wrec, bias, out, v_ws, s);
    }
}

// Round 6
// 1550.646 us; speedup vs baseline: 17.4064x; 1.2880x over previous
//
#include <hip/hip_runtime.h>

#define T_STEPS 128
#define BATCH   64
#define INDIM   512
#define HDIM    1024
#define NE      819
#define OUT0_SZ (T_STEPS*BATCH*HDIM)
#define BH      (BATCH*HDIM)          /* 65536 */
#define ALLH_L  (129*BH)

#define HS_LAY   131072               /* shorts per (parity,layer): 2 planes x 65536 */
#define HS_PAR   393216               /* shorts per parity (3 layers) */
#define XF_T     65536                /* shorts per timestep of x-frags: hi 32768 + lo 32768 */

typedef short bf16x8 __attribute__((ext_vector_type(8)));
typedef short short2v __attribute__((ext_vector_type(2)));
typedef float f32x4  __attribute__((ext_vector_type(4)));
typedef float f32x2  __attribute__((ext_vector_type(2)));

__device__ __forceinline__ short f2bf(float f){
    unsigned u = __float_as_uint(f);
    u += 0x7FFF + ((u >> 16) & 1);           /* RNE */
    return (short)(u >> 16);
}
__device__ __forceinline__ float bf2f(short s){
    return __uint_as_float(((unsigned)(unsigned short)s) << 16);
}

/* ============ one-time prep: weights -> |.|*sign*emask, split hi/lo, frag-swizzled ============ */
/* layout per layer: [it(64)][kb(nkb)][hi(512)|lo(512)] shorts; L0 nkb=48, L1/2 nkb=64 */
__global__ __launch_bounds__(256) void ei_prep_w(const float* __restrict__ Win0,
        const float* __restrict__ Win1, const float* __restrict__ Win2,
        const float* __restrict__ Wrec, short* __restrict__ wf){
    int gid = blockIdx.x * 256 + threadIdx.x;      /* 0 .. 720895 */
    int j, local, nkb, kff; const float* Win; short* base;
    if (gid < 196608)      { j=0; local=gid;        nkb=48; kff=512;  Win=Win0; base=wf; }
    else if (gid < 458752) { j=1; local=gid-196608; nkb=64; kff=1024; Win=Win1; base=wf+3145728; }
    else                   { j=2; local=gid-458752; nkb=64; kff=1024; Win=Win2; base=wf+7340032; }
    int lane = local & 63;
    int fi   = local >> 6;                         /* it*nkb + kb */
    int kb   = fi % nkb;
    int it   = fi / nkb;
    int i    = it*16 + (lane & 15);
    int k0   = kb*32 + ((lane >> 4) << 3);
    const float* wrec_row = Wrec + ((size_t)j*HDIM + i)*HDIM;
    bf16x8 hv, lv;
    #pragma unroll
    for (int e = 0; e < 8; ++e){
        int k = k0 + e;
        float w;
        if (k < kff){
            w = fabsf(Win[(size_t)i*kff + k]);
            if (j != 0 && k >= NE) w = 0.f;        /* e_mask folded into ff weights */
        } else {
            int kr = k - kff;
            w = fabsf(wrec_row[kr]);
            if (kr >= NE) w = -w;                  /* Dale sign folded */
        }
        short h = f2bf(w);
        hv[e] = h;
        lv[e] = f2bf(w - bf2f(h));
    }
    short* dst = base + (size_t)fi*1024 + lane*8;
    *(bf16x8*)dst         = hv;
    *(bf16x8*)(dst + 512) = lv;
}

/* ============ one-time prep: x -> A-frag layout [t][plane][kb(16)][bt(4)][lane(64)][8] ============ */
/* per t: hi plane [0,32768) shorts, lo plane [32768,65536) */
__global__ __launch_bounds__(256) void ei_prep_xf(const float* __restrict__ x,
        short* __restrict__ xf){
    int gid = blockIdx.x * 256 + threadIdx.x;      /* 0 .. 524287 */
    int lane = gid & 63;
    int bt   = (gid >> 6) & 3;
    int kb   = (gid >> 8) & 15;
    int t    = gid >> 12;
    int b = bt*16 + (lane & 15);
    int k = kb*32 + ((lane >> 4) << 3);
    const float* src = x + ((size_t)t*BATCH + b)*INDIM + k;
    float4 v0 = *(const float4*)src;
    float4 v1 = *(const float4*)(src + 4);
    float f[8] = {v0.x,v0.y,v0.z,v0.w,v1.x,v1.y,v1.z,v1.w};
    bf16x8 hv, lv;
    #pragma unroll
    for (int e = 0; e < 8; ++e){
        short h = f2bf(f[e]);
        hv[e] = h; lv[e] = f2bf(f[e] - bf2f(h));
    }
    short* dst = xf + (size_t)t*XF_T + (((size_t)(kb*4 + bt)) << 9) + lane*8;
    *(bf16x8*)dst            = hv;
    *(bf16x8*)(dst + 32768)  = lv;
}

/* ============ init: all_h[l][0]=h0, v=0, h-frags (both parities) ============ */
__global__ __launch_bounds__(256) void ei_init3(const float* __restrict__ h0,
        float* __restrict__ out, float* __restrict__ v_ws, short* __restrict__ hf){
    int idx = blockIdx.x * 256 + threadIdx.x;      /* 0 .. 196607 */
    int l = idx >> 16, r = idx & 0xFFFF;
    float h = h0[r];
    out[OUT0_SZ + (size_t)l*ALLH_L + r] = h;
    v_ws[idx] = 0.f;
    if (idx < 24576){
        int lane = idx & 63, bt = (idx >> 6) & 3, kb = (idx >> 8) & 31, j = idx >> 13;
        int b = bt*16 + (lane & 15);
        int k = kb*32 + ((lane >> 4) << 3);
        const float* src = h0 + (size_t)b*HDIM + k;
        float4 v0 = *(const float4*)src;
        float4 v1 = *(const float4*)(src + 4);
        float f[8] = {v0.x,v0.y,v0.z,v0.w,v1.x,v1.y,v1.z,v1.w};
        bf16x8 hv, lv;
        #pragma unroll
        for (int e = 0; e < 8; ++e){
            short hh = f2bf(f[e]);
            hv[e] = hh; lv[e] = f2bf(f[e] - bf2f(hh));
        }
        int off = ((kb*4 + bt) << 9) + lane*8;
        short* b0 = hf + (size_t)j*HS_LAY + off;
        *(bf16x8*)b0           = hv;
        *(bf16x8*)(b0 + 65536) = lv;
        short* b1 = b0 + HS_PAR;
        *(bf16x8*)b1           = hv;
        *(bf16x8*)(b1 + 65536) = lv;
    }
}

/* ============ K-loop body v5: W loads hoisted up-front, A depth-2 reg pipeline ============ */
/* NKW = kb per wave; FFLO = lo-plane offset of ff frag buffer (32768 x, 65536 h) */
template<int NKW, int NKFF, int FFLO>
__device__ __forceinline__ void stage_body5(
        const short* __restrict__ pff, const short* __restrict__ prec,
        const short* __restrict__ wp, int kb0, int laneo, f32x4 acc[4])
{
    /* all W fragments for this wave's K-slice, issued first */
    bf16x8 wbh[NKW], wbl[NKW];
    #pragma unroll
    for (int kk = 0; kk < NKW; ++kk){
        const short* w0 = wp + ((kb0 + kk) << 10);
        wbh[kk] = *(const bf16x8*)w0;
        wbl[kk] = *(const bf16x8*)(w0 + 512);
    }
    /* A depth-2 double buffer, fully unrolled (compile-time indices only) */
    bf16x8 ah[2][4], al[2][4];
    auto loadA = [&](int kk, int buf){
        int kb = kb0 + kk;
        const short* pa; int lo;
        if (kb < NKFF){ pa = pff + (kb << 11); lo = FFLO; }
        else          { pa = prec + ((kb - NKFF) << 11); lo = 65536; }
        #pragma unroll
        for (int bt = 0; bt < 4; ++bt){
            ah[buf][bt] = *(const bf16x8*)(pa + (bt << 9) + laneo);
            al[buf][bt] = *(const bf16x8*)(pa + lo + (bt << 9) + laneo);
        }
    };
    loadA(0, 0);
    #pragma unroll
    for (int kk = 0; kk < NKW; ++kk){
        if (kk + 1 < NKW) loadA(kk + 1, (kk + 1) & 1);
        const int bf = kk & 1;
        #pragma unroll
        for (int bt = 0; bt < 4; ++bt)
            acc[bt] = __builtin_amdgcn_mfma_f32_16x16x32_bf16(ah[bf][bt], wbh[kk], acc[bt], 0,0,0);
        #pragma unroll
        for (int bt = 0; bt < 4; ++bt)
            acc[bt] = __builtin_amdgcn_mfma_f32_16x16x32_bf16(al[bf][bt], wbh[kk], acc[bt], 0,0,0);
        #pragma unroll
        for (int bt = 0; bt < 4; ++bt)
            acc[bt] = __builtin_amdgcn_mfma_f32_16x16x32_bf16(ah[bf][bt], wbl[kk], acc[bt], 0,0,0);
    }
}

/* ============ skewed step v5: 192 blocks x 512 thr (8 waves = 8 K-slices), rep=1 ============ */
__global__ __launch_bounds__(512, 2) void ei_stage5(
        const short* __restrict__ xf, const short* __restrict__ wf,
        const float* __restrict__ bias, float* __restrict__ out,
        float* __restrict__ v_ws, short* __restrict__ hf, int s)
{
    int j = blockIdx.x >> 6;
    int t = s - j;
    if (t < 0 || t >= T_STEPS) return;
    int it = blockIdx.x & 63;
    int wv = threadIdx.x >> 6, lane = threadIdx.x & 63;
    int laneo = lane * 8;
    int par_r = (s - 1) & 1, par_w = s & 1;
    const short* hfr  = hf + par_r*HS_PAR;
    const short* prec = hfr + j*HS_LAY;

    f32x4 acc[4] = {{0.f,0.f,0.f,0.f},{0.f,0.f,0.f,0.f},
                    {0.f,0.f,0.f,0.f},{0.f,0.f,0.f,0.f}};

    if (j == 0){
        const short* pff = xf + t*XF_T;
        const short* wp  = wf + it*48*1024 + laneo;
        stage_body5<6,16,32768>(pff, prec, wp, wv*6, laneo, acc);
    } else if (j == 1){
        const short* pff = hfr;                       /* layer 0 h-frags */
        const short* wp  = wf + 3145728 + it*64*1024 + laneo;
        stage_body5<8,32,65536>(pff, prec, wp, wv*8, laneo, acc);
    } else {
        const short* pff = hfr + HS_LAY;              /* layer 1 h-frags */
        const short* wp  = wf + 7340032 + it*64*1024 + laneo;
        stage_body5<8,32,65536>(pff, prec, wp, wv*8, laneo, acc);
    }

    /* partials -> LDS. C/D layout: col=lane&15, row=(lane>>4)*4+r [m89] */
    __shared__ float psum[8][64][18];
    {
        int r0 = (lane >> 4) << 2, l15 = lane & 15;
        #pragma unroll
        for (int bt = 0; bt < 4; ++bt)
            #pragma unroll
            for (int r = 0; r < 4; ++r)
                psum[wv][bt*16 + r0 + r][l15] = acc[bt][r];
    }
    __syncthreads();

    /* reduce 8 K-slices + fused epilogue; thread -> (b, 2 consecutive i) */
    int tx  = threadIdx.x;
    int b   = tx >> 3;
    int il0 = (tx & 7) << 1;
    float* allh = out + OUT0_SZ + ((size_t)(j*129 + t + 1))*BH;
    float* outp = out + (size_t)t*BH;
    short* hww  = hf + par_w*HS_PAR + j*HS_LAY;
    float sum0 = 0.f, sum1 = 0.f;
    #pragma unroll
    for (int w = 0; w < 8; ++w){
        f32x2 p = *(f32x2*)&psum[w][b][il0];
        sum0 += p[0]; sum1 += p[1];
    }
    int i = it*16 + il0;
    f32x2 bb = *(const f32x2*)&bias[j*HDIM + i];
    int vo = (j*BATCH + b)*HDIM + i;
    f32x2 vold = *(f32x2*)&v_ws[vo];
    float vn0 = 0.8f * vold[0] + 0.2f * (sum0 + bb[0]);
    float vn1 = 0.8f * vold[1] + 0.2f * (sum1 + bb[1]);
    f32x2 vnv = {vn0, vn1};
    *(f32x2*)&v_ws[vo] = vnv;
    float h0 = vn0 > 0.f ? vn0 : 0.f;
    float h1 = vn1 > 0.f ? vn1 : 0.f;
    f32x2 hv2 = {h0, h1};
    *(f32x2*)&allh[b*HDIM + i] = hv2;
    short hh0 = f2bf(h0), hl0 = f2bf(h0 - bf2f(hh0));
    short hh1 = f2bf(h1), hl1 = f2bf(h1 - bf2f(hh1));
    int kb  = i >> 5, btw = b >> 4;
    int lnw = (b & 15) + (((i >> 3) & 3) << 4);
    int off = ((kb*4 + btw) << 9) + lnw*8 + (i & 7);
    short2v hi2 = {hh0, hh1}, lo2 = {hl0, hl1};
    *(short2v*)(hww + off)         = hi2;
    *(short2v*)(hww + off + 65536) = lo2;
    if (j == 2){
        f32x2 o2 = {(i < NE) ? h0 : 0.f, (i + 1 < NE) ? h1 : 0.f};
        *(f32x2*)&outp[b*HDIM + i] = o2;
    }
}

/* ================= fp32 fallback path (kept for small ws_size) ================= */
__global__ __launch_bounds__(256) void ei_init(const float* __restrict__ h0,
                                               float* __restrict__ out,
                                               float* __restrict__ v_ws) {
    int idx = blockIdx.x * 256 + threadIdx.x;
    int l = idx >> 16, r = idx & 0xFFFF;
    out[OUT0_SZ + (size_t)l*ALLH_L + r] = h0[r];
    v_ws[idx] = 0.0f;
}

__global__ __launch_bounds__(256) void ei_stage(
    const float* __restrict__ xin, const float* __restrict__ Win0,
    const float* __restrict__ Win1, const float* __restrict__ Win2,
    const float* __restrict__ Wrec, const float* __restrict__ bias,
    float* __restrict__ out, float* __restrict__ v_ws, int s)
{
    const int j  = blockIdx.x >> 6;
    const int cb = blockIdx.x & 63;
    const int t  = s - j;
    if (t < 0 || t >= T_STEPS) return;
    float* all_h = out + OUT0_SZ;
    const float* Win = (j == 0) ? Win0 : (j == 1 ? Win1 : Win2);
    const int K1 = (j == 0) ? INDIM : HDIM;
    const float* Wr = Wrec + j * HDIM * HDIM;
    const float* ffp; int ffld;
    if (j == 0) { ffp = xin + (size_t)t * BATCH * INDIM; ffld = INDIM; }
    else        { ffp = all_h + ((size_t)(j - 1) * 129 + (t + 1)) * BH; ffld = HDIM; }
    const float* hj = all_h + ((size_t)j * 129 + t) * BH;
    __shared__ float Xs[64][68];
    __shared__ float Ws[16][65];
    const int tx = threadIdx.x;
    const int i_loc = tx & 15;
    const int b0 = (tx >> 4) * 4;
    const int i0 = cb * 16;
    float acc0 = 0.f, acc1 = 0.f, acc2 = 0.f, acc3 = 0.f;
    const int nch_ff = K1 >> 6;
    const int nch = nch_ff + (HDIM >> 6);
    for (int ch = 0; ch < nch; ++ch) {
        const bool ff = ch < nch_ff;
        const int kb = ff ? (ch << 6) : ((ch - nch_ff) << 6);
        __syncthreads();
        #pragma unroll
        for (int itr = 0; itr < 16; ++itr) {
            int idx = itr * 256 + tx;
            int bl = idx >> 6, kl = idx & 63, k = kb + kl;
            float v;
            if (ff) { v = ffp[bl * ffld + k]; if (j != 0 && k >= NE) v = 0.0f; }
            else    { v = hj[bl * HDIM + k];  if (k >= NE) v = -v; }
            Xs[kl][bl] = v;
        }
        const float* W = ff ? Win : Wr;
        const int ldw = ff ? K1 : HDIM;
        #pragma unroll
        for (int itr = 0; itr < 4; ++itr) {
            int idx = itr * 256 + tx;
            int il = idx >> 6, kl = idx & 63;
            Ws[il][kl] = fabsf(W[(i0 + il) * ldw + kb + kl]);
        }
        __syncthreads();
        #pragma unroll
        for (int kk = 0; kk < 64; ++kk) {
            const float w = Ws[i_loc][kk];
            const float4 x4 = *reinterpret_cast<const float4*>(&Xs[kk][b0]);
            acc0 = fmaf(x4.x, w, acc0); acc1 = fmaf(x4.y, w, acc1);
            acc2 = fmaf(x4.z, w, acc2); acc3 = fmaf(x4.w, w, acc3);
        }
    }
    const int i = i0 + i_loc;
    const float bj = bias[j * HDIM + i];
    float accs[4] = {acc0, acc1, acc2, acc3};
    #pragma unroll
    for (int r = 0; r < 4; ++r) {
        const int b = b0 + r;
        const float pre = accs[r] + bj;
        float* vp = v_ws + ((size_t)j * BATCH + b) * HDIM + i;
        const float vn = 0.8f * (*vp) + 0.2f * pre;
        *vp = vn;
        const float h = vn > 0.f ? vn : 0.f;
        all_h[((size_t)j * 129 + (t + 1)) * BH + b * HDIM + i] = h;
        if (j == 2) out[((size_t)t * BATCH + b) * HDIM + i] = (i < NE) ? h : 0.f;
    }
}

extern "C" void kernel_launch(void* const* d_in, const int* in_sizes, int n_in,
                              void* d_out, int out_size, void* d_ws, size_t ws_size,
                              hipStream_t stream) {
    const float* xin  = (const float*)d_in[0];
    const float* h0   = (const float*)d_in[1];
    const float* Win0 = (const float*)d_in[2];
    const float* Win1 = (const float*)d_in[3];
    const float* Win2 = (const float*)d_in[4];
    const float* Wrec = (const float*)d_in[5];
    const float* bias = (const float*)d_in[6];
    float* out  = (float*)d_out;
    char* ws    = (char*)d_ws;

    /* layout: v(786432) | hf(1572864) | xf(16777216) | wf(23068672) */
    const size_t need = 786432ULL + 1572864ULL + 16777216ULL + 23068672ULL; /* 42205184 */

    if (ws_size >= need) {
        float* v_ws = (float*)ws;
        short* hf   = (short*)(ws + 786432);
        short* xf   = (short*)(ws + 786432 + 1572864ULL);
        short* wfp  = (short*)(ws + 786432 + 1572864ULL + 16777216ULL);
        hipLaunchKernelGGL(ei_prep_w, dim3(2816), dim3(256), 0, stream,
                           Win0, Win1, Win2, Wrec, wfp);
        hipLaunchKernelGGL(ei_prep_xf, dim3(2048), dim3(256), 0, stream, xin, xf);
        hipLaunchKernelGGL(ei_init3, dim3(768), dim3(256), 0, stream, h0, out, v_ws, hf);
        for (int s = 0; s < T_STEPS + 2; ++s)
            hipLaunchKernelGGL(ei_stage5, dim3(192), dim3(512), 0, stream,
                               xf, wfp, bias, out, v_ws, hf, s);
    } else {
        float* v_ws = (float*)ws;
        hipLaunchKernelGGL(ei_init, dim3(768), dim3(256), 0, stream, h0, out, v_ws);
        for (int s = 0; s < T_STEPS + 2; ++s)
            hipLaunchKernelGGL(ei_stage, dim3(192), dim3(256), 0, stream,
                               xin, Win0, Win1, Win2, Wrec, bias, out, v_ws, s);
    }
}